// Round 1
// baseline (690.221 us; speedup 1.0000x reference)
//
#include <hip/hip_runtime.h>
#include <stdint.h>
#include <math.h>

// Problem constants (fixed by the reference setup_inputs).
#define PP 131072   // priors
#define BB 32       // batch
#define AA 32       // truths per image
#define THRESH 0.35f

// ws layout (bytes):
//   0    : double accL[32]          (smooth-L1 loc loss, per batch)
//   256  : double accC[32]          (conf loss, per batch)
//   512  : double accLM[32]         (landmark loss, per batch)
//   768  : int    numpos[32]
//   1024 : u64    slots[BB*AA]      (packed per-truth argmax over priors)
//   16384: u8     bti[BB*PP]        (per-prior best-truth idx | flag<<5)   4 MiB
//   16384+4MiB : float loss_mine[BB*PP]                                   16 MiB
static constexpr size_t OFF_ACCL = 0;
static constexpr size_t OFF_ACCC = 256;
static constexpr size_t OFF_ACCLM = 512;
static constexpr size_t OFF_NP = 768;
static constexpr size_t OFF_SLOT = 1024;
static constexpr size_t OFF_BTI = 16384;
static constexpr size_t OFF_LM = 16384 + (size_t)BB * PP;

// ---------------------------------------------------------------------------
// K1: per-prior best truth (cross-mult compares, no divides) + per-truth best
// prior (packed u64 atomicMax; value=iou bits, tie -> smaller prior index).
// Grid: (PP/2048, BB) x 256 threads; each thread owns 8 priors in registers.
// ---------------------------------------------------------------------------
__global__ __launch_bounds__(256) void k_match(
    const float* __restrict__ priors, const float* __restrict__ targets,
    unsigned long long* __restrict__ slots, unsigned char* __restrict__ bti) {
#pragma clang fp contract(off)
  const int b = blockIdx.y;
  const int tid = threadIdx.x;
  __shared__ float tx0[AA], ty0[AA], tx1[AA], ty1[AA], tar[AA];
  if (tid < AA) {
    const float* tg = targets + ((size_t)b * AA + tid) * 15;
    float a0 = tg[0], a1 = tg[1], a2 = tg[2], a3 = tg[3];
    tx0[tid] = a0; ty0[tid] = a1; tx1[tid] = a2; ty1[tid] = a3;
    tar[tid] = (a2 - a0) * (a3 - a1);
  }
  __syncthreads();

  const int base = blockIdx.x * 2048;
  // 8 priors per thread, resident in registers.
  float px0[8], py0[8], px1[8], py1[8], areaB[8];
  float cbi[8], cbd[8];  // per-prior best (inter, denom)
  int cba[8];
#pragma unroll
  for (int i = 0; i < 8; ++i) {
    const int p = base + i * 256 + tid;
    const float4 pr = reinterpret_cast<const float4*>(priors)[p];
    const float hx = pr.z * 0.5f, hy = pr.w * 0.5f;
    px0[i] = pr.x - hx; py0[i] = pr.y - hy;
    px1[i] = pr.x + hx; py1[i] = pr.y + hy;
    areaB[i] = (px1[i] - px0[i]) * (py1[i] - py0[i]);
    cbi[i] = -1.f; cbd[i] = 1.f; cba[i] = 0;
  }

  const int lane = tid & 63;
  for (int a = 0; a < AA; ++a) {
    const float sx0 = tx0[a], sy0 = ty0[a], sx1 = tx1[a], sy1 = ty1[a];
    const float sar = tar[a];
    float bi = -1.f, bd = 1.f;  // this truth's best over my 8 priors
    int bp = 0;
#pragma unroll
    for (int i = 0; i < 8; ++i) {
      const float lx = fmaxf(sx0, px0[i]);
      const float ly = fmaxf(sy0, py0[i]);
      const float rx = fminf(sx1, px1[i]);
      const float ry = fminf(sy1, py1[i]);
      const float wx = fmaxf(rx - lx, 0.f);
      const float wy = fmaxf(ry - ly, 0.f);
      const float inter = wx * wy;
      const float den = sar + areaB[i] - inter;
      // per-prior best over truths (strict >, a ascending => first occurrence)
      if (inter * cbd[i] > cbi[i] * den) { cbi[i] = inter; cbd[i] = den; cba[i] = a; }
      // per-truth best over priors (strict >, p ascending within thread)
      if (inter * bd > bi * den) { bi = inter; bd = den; bp = base + i * 256 + tid; }
    }
    // wave butterfly reduce: max iou, tie -> smaller prior index
    const float r = bi / bd;
    unsigned long long key =
        ((unsigned long long)__float_as_uint(r) << 32) |
        (unsigned long long)(0xFFFFFFFFu - (unsigned)bp);
#pragma unroll
    for (int off = 1; off < 64; off <<= 1) {
      unsigned long long o = __shfl_xor(key, off, 64);
      if (o > key) key = o;
    }
    if (lane == 0) atomicMax(&slots[b * AA + a], key);
  }

#pragma unroll
  for (int i = 0; i < 8; ++i) {
    const int p = base + i * 256 + tid;
    const float r = cbi[i] / cbd[i];
    bti[(size_t)b * PP + p] =
        (unsigned char)cba[i] | ((r < THRESH) ? 0 : 32);
  }
}

// ---------------------------------------------------------------------------
// K2: override + conf loss for all priors (writes loss_mine), sparse loc /
// landmark losses for positives. Per-batch double accumulators.
// ---------------------------------------------------------------------------
__global__ __launch_bounds__(256) void k_loss(
    const float* __restrict__ loc, const float* __restrict__ conf,
    const float* __restrict__ loc5, const float* __restrict__ priors,
    const float* __restrict__ targets,
    const unsigned long long* __restrict__ slots,
    const unsigned char* __restrict__ bti, float* __restrict__ lossm,
    double* __restrict__ accL, double* __restrict__ accC,
    double* __restrict__ accLM, int* __restrict__ numpos) {
#pragma clang fp contract(off)
  const int b = blockIdx.y;
  const int tid = threadIdx.x;
  __shared__ float tr[AA][15];
  __shared__ int ovr[AA];
  if (tid < AA) {
    const float* tg = targets + ((size_t)b * AA + tid) * 15;
#pragma unroll
    for (int j = 0; j < 15; ++j) tr[tid][j] = tg[j];
    const unsigned long long key = slots[b * AA + tid];
    ovr[tid] = (int)(0xFFFFFFFFu - (unsigned)(key & 0xFFFFFFFFull));
  }
  __syncthreads();
  // override prior ids in registers (broadcast once, reused for 8 priors)
  int ov[AA];
#pragma unroll
  for (int a = 0; a < AA; ++a) ov[a] = ovr[a];

  double ll = 0.0, lc = 0.0, lm = 0.0;
  int np = 0;
  const int base = blockIdx.x * 2048;
  for (int it = 0; it < 8; ++it) {
    const int p = base + it * 256 + tid;
    const size_t gp = (size_t)b * PP + p;
    const unsigned char f = bti[gp];
    int idx = f & 31;
    bool posf = (f & 32) != 0;
#pragma unroll
    for (int a = 0; a < AA; ++a)
      if (ov[a] == p) { idx = a; posf = true; }  // last truth wins
    const int cls = posf ? (int)tr[idx][4] : 0;
    const bool pos = cls > 0;

    const float2 cc = reinterpret_cast<const float2*>(conf)[gp];
    const float mx = fmaxf(cc.x, cc.y);
    const float lse = mx + logf(expf(cc.x - mx) + expf(cc.y - mx));
    const float gtl = (cls >= 1) ? cc.y : cc.x;
    const float lca = lse - gtl;
    lossm[gp] = pos ? 0.f : lca;

    if (pos) {
      ++np;
      lc += (double)lca;
      const float4 pr = reinterpret_cast<const float4*>(priors)[p];
      const float m0 = tr[idx][0], m1 = tr[idx][1];
      const float m2 = tr[idx][2], m3 = tr[idx][3];
      const float vx = 0.1f * pr.z, vy = 0.1f * pr.w;
      const float t0 = ((m0 + m2) / 2.0f - pr.x) / vx;
      const float t1 = ((m1 + m3) / 2.0f - pr.y) / vy;
      const float t2 = logf((m2 - m0) / pr.z) / 0.2f;
      const float t3 = logf((m3 - m1) / pr.w) / 0.2f;
      const float* lp = loc + gp * 4;
      float s = 0.f;
      {
        float d = lp[0] - t0, ad = fabsf(d);
        s += (ad < 1.f) ? 0.5f * d * d : ad - 0.5f;
        d = lp[1] - t1; ad = fabsf(d);
        s += (ad < 1.f) ? 0.5f * d * d : ad - 0.5f;
        d = lp[2] - t2; ad = fabsf(d);
        s += (ad < 1.f) ? 0.5f * d * d : ad - 0.5f;
        d = lp[3] - t3; ad = fabsf(d);
        s += (ad < 1.f) ? 0.5f * d * d : ad - 0.5f;
      }
      ll += (double)s;
      const float* l5 = loc5 + gp * 10;
      float s2 = 0.f;
#pragma unroll
      for (int j = 0; j < 5; ++j) {
        const float tx = (tr[idx][5 + 2 * j] - pr.x) / vx;
        const float ty = (tr[idx][6 + 2 * j] - pr.y) / vy;
        const float dx = l5[2 * j] - tx;
        const float dy = l5[2 * j + 1] - ty;
        s2 += dx * dx + dy * dy;
      }
      lm += (double)s2;
    }
  }
  // wave butterfly then cross-wave LDS reduce, one atomic per block per acc
#pragma unroll
  for (int off = 1; off < 64; off <<= 1) {
    ll += __shfl_xor(ll, off, 64);
    lc += __shfl_xor(lc, off, 64);
    lm += __shfl_xor(lm, off, 64);
    np += __shfl_xor(np, off, 64);
  }
  __shared__ double rl[4], rc[4], rm[4];
  __shared__ int rn[4];
  const int wave = tid >> 6, lane = tid & 63;
  if (lane == 0) { rl[wave] = ll; rc[wave] = lc; rm[wave] = lm; rn[wave] = np; }
  __syncthreads();
  if (tid == 0) {
    atomicAdd(&accL[b], rl[0] + rl[1] + rl[2] + rl[3]);
    atomicAdd(&accC[b], rc[0] + rc[1] + rc[2] + rc[3]);
    atomicAdd(&accLM[b], rm[0] + rm[1] + rm[2] + rm[3]);
    atomicAdd(&numpos[b], rn[0] + rn[1] + rn[2] + rn[3]);
  }
}

// ---------------------------------------------------------------------------
// K3: per-batch radix select (4 x 8-bit passes over float bits; loss_mine >= 0
// so bits are uint-monotonic). loss_c top-K sum = sum(v>thr) + krem*thr.
// ---------------------------------------------------------------------------
__global__ __launch_bounds__(512) void k_topk(
    const float* __restrict__ lossm, const int* __restrict__ numpos,
    double* __restrict__ accC) {
  const int b = blockIdx.x;
  const int tid = threadIdx.x;
  __shared__ unsigned hist[256];
  __shared__ unsigned sh_bin, sh_krem;
  const int np = numpos[b];
  long long K = 7LL * np;
  if (K > PP - 1) K = PP - 1;
  if (K <= 0) return;  // uniform across block
  const float* v = lossm + (size_t)b * PP;
  unsigned prefix = 0;
  unsigned krem = (unsigned)K;
  for (int s = 24; s >= 0; s -= 8) {
    if (tid < 256) hist[tid] = 0;
    __syncthreads();
    const unsigned mask = (s == 24) ? 0u : (0xFFFFFFFFu << (s + 8));
    for (int i = tid; i < PP; i += 512) {
      const unsigned u = __float_as_uint(v[i]);
      if ((u & mask) == prefix) atomicAdd(&hist[(u >> s) & 0xFFu], 1u);
    }
    __syncthreads();
    if (tid == 0) {
      unsigned cum = 0;
      int bin = 0;
      for (int i2 = 255; i2 >= 0; --i2) {
        cum += hist[i2];
        if (cum >= krem) { bin = i2; break; }
      }
      sh_bin = (unsigned)bin;
      sh_krem = krem - (cum - hist[bin]);
    }
    __syncthreads();
    prefix |= sh_bin << s;
    krem = sh_krem;
  }
  const float thr = __uint_as_float(prefix);
  double sum = 0.0;
  for (int i = tid; i < PP; i += 512) {
    const float x = v[i];
    if (__float_as_uint(x) > prefix) sum += (double)x;
  }
#pragma unroll
  for (int off = 1; off < 64; off <<= 1) sum += __shfl_xor(sum, off, 64);
  __shared__ double rs[8];
  const int wave = tid >> 6, lane = tid & 63;
  if (lane == 0) rs[wave] = sum;
  __syncthreads();
  if (tid == 0) {
    double t = rs[0] + rs[1] + rs[2] + rs[3] + rs[4] + rs[5] + rs[6] + rs[7];
    t += (double)krem * (double)thr;
    accC[b] += t;  // only writer of accC[b] at this point in the stream
  }
}

// ---------------------------------------------------------------------------
// K4: finalize -> d_out[3] = {loss_l/N, loss_c/N, loss_coords/N}
// ---------------------------------------------------------------------------
__global__ void k_final(const double* __restrict__ accL,
                        const double* __restrict__ accC,
                        const double* __restrict__ accLM,
                        const int* __restrict__ numpos,
                        float* __restrict__ out) {
  if (threadIdx.x == 0 && blockIdx.x == 0) {
    long long tot = 0;
    double sl = 0, sc = 0, sm = 0;
    for (int b = 0; b < BB; ++b) {
      tot += numpos[b];
      sl += accL[b];
      sc += accC[b];
      sm += accLM[b];
    }
    float N = (float)tot;
    if (N < 1.f) N = 1.f;
    out[0] = (float)(sl / (double)N);
    out[1] = (float)(sc / (double)N);
    out[2] = (float)(sm / (double)N);
  }
}

extern "C" void kernel_launch(void* const* d_in, const int* in_sizes, int n_in,
                              void* d_out, int out_size, void* d_ws,
                              size_t ws_size, hipStream_t stream) {
  const float* loc = (const float*)d_in[0];
  const float* conf = (const float*)d_in[1];
  const float* loc5 = (const float*)d_in[2];
  const float* priors = (const float*)d_in[3];
  const float* tgt = (const float*)d_in[4];
  char* ws = (char*)d_ws;
  double* accL = (double*)(ws + OFF_ACCL);
  double* accC = (double*)(ws + OFF_ACCC);
  double* accLM = (double*)(ws + OFF_ACCLM);
  int* numpos = (int*)(ws + OFF_NP);
  unsigned long long* slots = (unsigned long long*)(ws + OFF_SLOT);
  unsigned char* bti = (unsigned char*)(ws + OFF_BTI);
  float* lossm = (float*)(ws + OFF_LM);

  // zero accumulators + argmax slots (9216 bytes); ws arrives poisoned 0xAA
  hipMemsetAsync(d_ws, 0, OFF_SLOT + (size_t)BB * AA * 8, stream);

  dim3 grid(PP / 2048, BB);
  k_match<<<grid, 256, 0, stream>>>(priors, tgt, slots, bti);
  k_loss<<<grid, 256, 0, stream>>>(loc, conf, loc5, priors, tgt, slots, bti,
                                   lossm, accL, accC, accLM, numpos);
  k_topk<<<BB, 512, 0, stream>>>(lossm, numpos, accC);
  k_final<<<1, 64, 0, stream>>>(accL, accC, accLM, numpos, (float*)d_out);
}

// Round 4
// 519.753 us; speedup vs baseline: 1.3280x; 1.3280x over previous
//
#include <hip/hip_runtime.h>
#include <stdint.h>
#include <math.h>

// Problem constants (fixed by the reference setup_inputs).
#define PP 131072   // priors
#define BB 32       // batch
#define AA 32       // truths per image
#define THRESH 0.35f

// ws layout (bytes) — IDENTICAL total footprint to the round-1 passing run:
//   0    : double accL[32]
//   256  : double accC[32]
//   512  : double accLM[32]
//   768  : int    numpos[32]
//   1024 : u64    slots[BB*AA]                                 8 KiB
//   9216 : u32    sel[BB][4]  (prefix, krem)                   512 B
//   16384: u8     bti[BB*PP]                                   4 MiB
//          ^-- u32 hist[BB][2048] ALIASES bti (bti dead after k_loss)
//   OFF_LM : float loss_mine[BB*PP]                            16 MiB
static constexpr size_t OFF_ACCL = 0;
static constexpr size_t OFF_ACCC = 256;
static constexpr size_t OFF_ACCLM = 512;
static constexpr size_t OFF_NP = 768;
static constexpr size_t OFF_SLOT = 1024;
static constexpr size_t OFF_SEL = 9216;
static constexpr size_t OFF_BTI = 16384;
static constexpr size_t OFF_HIST = OFF_BTI;  // alias, see above
static constexpr size_t OFF_LM = 16384 + (size_t)BB * PP;

// ---------------------------------------------------------------------------
// K1: per-prior best truth (cross-mult compares, no divides) + per-truth best
// prior (packed u64 atomicMax; value=iou bits, tie -> smaller prior index).
// Grid: (PP/2048, BB) x 256 threads; each thread owns 8 priors in registers.
// ---------------------------------------------------------------------------
__global__ __launch_bounds__(256) void k_match(
    const float* __restrict__ priors, const float* __restrict__ targets,
    unsigned long long* __restrict__ slots, unsigned char* __restrict__ bti) {
#pragma clang fp contract(off)
  const int b = blockIdx.y;
  const int tid = threadIdx.x;
  __shared__ float tx0[AA], ty0[AA], tx1[AA], ty1[AA], tar[AA];
  if (tid < AA) {
    const float* tg = targets + ((size_t)b * AA + tid) * 15;
    float a0 = tg[0], a1 = tg[1], a2 = tg[2], a3 = tg[3];
    tx0[tid] = a0; ty0[tid] = a1; tx1[tid] = a2; ty1[tid] = a3;
    tar[tid] = (a2 - a0) * (a3 - a1);
  }
  __syncthreads();

  const int base = blockIdx.x * 2048;
  float px0[8], py0[8], px1[8], py1[8], areaB[8];
  float cbi[8], cbd[8];
  int cba[8];
#pragma unroll
  for (int i = 0; i < 8; ++i) {
    const int p = base + i * 256 + tid;
    const float4 pr = reinterpret_cast<const float4*>(priors)[p];
    const float hx = pr.z * 0.5f, hy = pr.w * 0.5f;
    px0[i] = pr.x - hx; py0[i] = pr.y - hy;
    px1[i] = pr.x + hx; py1[i] = pr.y + hy;
    areaB[i] = (px1[i] - px0[i]) * (py1[i] - py0[i]);
    cbi[i] = -1.f; cbd[i] = 1.f; cba[i] = 0;
  }

  const int lane = tid & 63;
  for (int a = 0; a < AA; ++a) {
    const float sx0 = tx0[a], sy0 = ty0[a], sx1 = tx1[a], sy1 = ty1[a];
    const float sar = tar[a];
    float bi = -1.f, bd = 1.f;
    int bp = 0;
#pragma unroll
    for (int i = 0; i < 8; ++i) {
      const float lx = fmaxf(sx0, px0[i]);
      const float ly = fmaxf(sy0, py0[i]);
      const float rx = fminf(sx1, px1[i]);
      const float ry = fminf(sy1, py1[i]);
      const float wx = fmaxf(rx - lx, 0.f);
      const float wy = fmaxf(ry - ly, 0.f);
      const float inter = wx * wy;
      const float den = sar + areaB[i] - inter;
      if (inter * cbd[i] > cbi[i] * den) { cbi[i] = inter; cbd[i] = den; cba[i] = a; }
      if (inter * bd > bi * den) { bi = inter; bd = den; bp = base + i * 256 + tid; }
    }
    const float r = bi / bd;
    unsigned long long key =
        ((unsigned long long)__float_as_uint(r) << 32) |
        (unsigned long long)(0xFFFFFFFFu - (unsigned)bp);
#pragma unroll
    for (int off = 1; off < 64; off <<= 1) {
      unsigned long long o = __shfl_xor(key, off, 64);
      if (o > key) key = o;
    }
    if (lane == 0) atomicMax(&slots[b * AA + a], key);
  }

#pragma unroll
  for (int i = 0; i < 8; ++i) {
    const int p = base + i * 256 + tid;
    const float r = cbi[i] / cbd[i];
    bti[(size_t)b * PP + p] =
        (unsigned char)cba[i] | ((r < THRESH) ? 0 : 32);
  }
}

// ---------------------------------------------------------------------------
// K2: override + conf loss for all priors (writes loss_mine), sparse loc /
// landmark losses for positives. Per-batch double accumulators.
// ---------------------------------------------------------------------------
__global__ __launch_bounds__(256) void k_loss(
    const float* __restrict__ loc, const float* __restrict__ conf,
    const float* __restrict__ loc5, const float* __restrict__ priors,
    const float* __restrict__ targets,
    const unsigned long long* __restrict__ slots,
    const unsigned char* __restrict__ bti, float* __restrict__ lossm,
    double* __restrict__ accL, double* __restrict__ accC,
    double* __restrict__ accLM, int* __restrict__ numpos) {
#pragma clang fp contract(off)
  const int b = blockIdx.y;
  const int tid = threadIdx.x;
  __shared__ float tr[AA][15];
  __shared__ int ovr[AA];
  if (tid < AA) {
    const float* tg = targets + ((size_t)b * AA + tid) * 15;
#pragma unroll
    for (int j = 0; j < 15; ++j) tr[tid][j] = tg[j];
    const unsigned long long key = slots[b * AA + tid];
    ovr[tid] = (int)(0xFFFFFFFFu - (unsigned)(key & 0xFFFFFFFFull));
  }
  __syncthreads();
  int ov[AA];
#pragma unroll
  for (int a = 0; a < AA; ++a) ov[a] = ovr[a];

  double ll = 0.0, lc = 0.0, lm = 0.0;
  int np = 0;
  const int base = blockIdx.x * 2048;
  for (int it = 0; it < 8; ++it) {
    const int p = base + it * 256 + tid;
    const size_t gp = (size_t)b * PP + p;
    const unsigned char f = bti[gp];
    int idx = f & 31;
    bool posf = (f & 32) != 0;
#pragma unroll
    for (int a = 0; a < AA; ++a)
      if (ov[a] == p) { idx = a; posf = true; }
    const int cls = posf ? (int)tr[idx][4] : 0;
    const bool pos = cls > 0;

    const float2 cc = reinterpret_cast<const float2*>(conf)[gp];
    const float mx = fmaxf(cc.x, cc.y);
    const float lse = mx + logf(expf(cc.x - mx) + expf(cc.y - mx));
    const float gtl = (cls >= 1) ? cc.y : cc.x;
    const float lca = lse - gtl;
    lossm[gp] = pos ? 0.f : lca;

    if (pos) {
      ++np;
      lc += (double)lca;
      const float4 pr = reinterpret_cast<const float4*>(priors)[p];
      const float m0 = tr[idx][0], m1 = tr[idx][1];
      const float m2 = tr[idx][2], m3 = tr[idx][3];
      const float vx = 0.1f * pr.z, vy = 0.1f * pr.w;
      const float t0 = ((m0 + m2) / 2.0f - pr.x) / vx;
      const float t1 = ((m1 + m3) / 2.0f - pr.y) / vy;
      const float t2 = logf((m2 - m0) / pr.z) / 0.2f;
      const float t3 = logf((m3 - m1) / pr.w) / 0.2f;
      const float* lp = loc + gp * 4;
      float s = 0.f;
      {
        float d = lp[0] - t0, ad = fabsf(d);
        s += (ad < 1.f) ? 0.5f * d * d : ad - 0.5f;
        d = lp[1] - t1; ad = fabsf(d);
        s += (ad < 1.f) ? 0.5f * d * d : ad - 0.5f;
        d = lp[2] - t2; ad = fabsf(d);
        s += (ad < 1.f) ? 0.5f * d * d : ad - 0.5f;
        d = lp[3] - t3; ad = fabsf(d);
        s += (ad < 1.f) ? 0.5f * d * d : ad - 0.5f;
      }
      ll += (double)s;
      const float* l5 = loc5 + gp * 10;
      float s2 = 0.f;
#pragma unroll
      for (int j = 0; j < 5; ++j) {
        const float tx = (tr[idx][5 + 2 * j] - pr.x) / vx;
        const float ty = (tr[idx][6 + 2 * j] - pr.y) / vy;
        const float dx = l5[2 * j] - tx;
        const float dy = l5[2 * j + 1] - ty;
        s2 += dx * dx + dy * dy;
      }
      lm += (double)s2;
    }
  }
#pragma unroll
  for (int off = 1; off < 64; off <<= 1) {
    ll += __shfl_xor(ll, off, 64);
    lc += __shfl_xor(lc, off, 64);
    lm += __shfl_xor(lm, off, 64);
    np += __shfl_xor(np, off, 64);
  }
  __shared__ double rl[4], rc[4], rm[4];
  __shared__ int rn[4];
  const int wave = tid >> 6, lane = tid & 63;
  if (lane == 0) { rl[wave] = ll; rc[wave] = lc; rm[wave] = lm; rn[wave] = np; }
  __syncthreads();
  if (tid == 0) {
    atomicAdd(&accL[b], rl[0] + rl[1] + rl[2] + rl[3]);
    atomicAdd(&accC[b], rc[0] + rc[1] + rc[2] + rc[3]);
    atomicAdd(&accLM[b], rm[0] + rm[1] + rm[2] + rm[3]);
    atomicAdd(&numpos[b], rn[0] + rn[1] + rn[2] + rn[3]);
  }
}

// ---------------------------------------------------------------------------
// Radix-select pass: per-batch histogram of BITS bits at SHIFT, over elements
// whose higher bits match sel[b].prefix. Grid (8, BB) x 256; LDS-privatized
// histograms (exponent+mantissa spread -> low atomic contention), sparse
// flush to global per-batch histogram.
// ---------------------------------------------------------------------------
template <int SHIFT, int BITS>
__global__ __launch_bounds__(256) void k_hist(
    const float* __restrict__ lossm, const unsigned* __restrict__ sel,
    unsigned* __restrict__ hist) {
  const int b = blockIdx.y;
  const int tid = threadIdx.x;
  constexpr int NBINS = 1 << BITS;
  __shared__ unsigned h[NBINS];
  for (int i = tid; i < NBINS; i += 256) h[i] = 0;
  __syncthreads();
  const unsigned hmask =
      (SHIFT + BITS >= 32) ? 0u : (0xFFFFFFFFu << (SHIFT + BITS));
  const unsigned pref = (SHIFT + BITS >= 32) ? 0u : (sel[b * 4] & hmask);
  const float4* v4 = reinterpret_cast<const float4*>(lossm + (size_t)b * PP) +
                     (size_t)blockIdx.x * 4096;
#pragma unroll 4
  for (int k = 0; k < 16; ++k) {
    const float4 x = v4[tid + k * 256];
    const unsigned u0 = __float_as_uint(x.x), u1 = __float_as_uint(x.y);
    const unsigned u2 = __float_as_uint(x.z), u3 = __float_as_uint(x.w);
    if ((u0 & hmask) == pref) atomicAdd(&h[(u0 >> SHIFT) & (NBINS - 1)], 1u);
    if ((u1 & hmask) == pref) atomicAdd(&h[(u1 >> SHIFT) & (NBINS - 1)], 1u);
    if ((u2 & hmask) == pref) atomicAdd(&h[(u2 >> SHIFT) & (NBINS - 1)], 1u);
    if ((u3 & hmask) == pref) atomicAdd(&h[(u3 >> SHIFT) & (NBINS - 1)], 1u);
  }
  __syncthreads();
  unsigned* H = hist + b * 2048;
  for (int i = tid; i < NBINS; i += 256) {
    const unsigned c = h[i];
    if (c) atomicAdd(&H[i], c);
  }
}

// ---------------------------------------------------------------------------
// Select the bin containing the krem-th largest value; update prefix/krem;
// zero the histogram for the next pass. 32 blocks (one per batch).
// ---------------------------------------------------------------------------
template <int SHIFT, int BITS, bool FIRST>
__global__ __launch_bounds__(256) void k_select(
    unsigned* __restrict__ hist, unsigned* __restrict__ sel,
    const int* __restrict__ numpos) {
  const int b = blockIdx.x;
  const int tid = threadIdx.x;
  constexpr int NBINS = 1 << BITS;
  constexpr int CH = NBINS / 256;
  unsigned* H = hist + b * 2048;
  __shared__ unsigned hb[2048];
  __shared__ unsigned csum[256];
  __shared__ unsigned s_krem;
  if (tid == 0) {
    if (FIRST) {
      long long K = 7LL * (long long)numpos[b];
      if (K > PP - 1) K = PP - 1;
      if (K <= 0) {
        s_krem = 0;
        sel[b * 4] = 0xFFFFFFFFu;  // sentinel: selects nothing
        sel[b * 4 + 1] = 0;
      } else {
        s_krem = (unsigned)K;
      }
    } else {
      s_krem = sel[b * 4 + 1];
    }
  }
  for (int i = tid; i < NBINS; i += 256) hb[i] = H[i];
  __syncthreads();
  // per-thread chunk sums (chunks ordered by descending bin index)
  const int start = NBINS - 1 - tid * CH;
  unsigned msum = 0;
#pragma unroll
  for (int j = 0; j < CH; ++j) msum += hb[start - j];
  csum[tid] = msum;
  // zero global histogram for the next pass
  for (int i = tid; i < 2048; i += 256) H[i] = 0;
  __syncthreads();
  if (tid == 0) {
    unsigned krem = s_krem;
    if (krem > 0) {
      unsigned cum = 0;
      int c = 0;
      while (c < 255 && cum + csum[c] < krem) { cum += csum[c]; ++c; }
      const int st = NBINS - 1 - c * CH;
      int bin = st - (CH - 1);
      for (int j = 0; j < CH; ++j) {
        const unsigned hh = hb[st - j];
        if (cum + hh >= krem) { bin = st - j; break; }
        cum += hh;
      }
      unsigned pref = FIRST ? 0u : sel[b * 4];
      pref |= ((unsigned)bin) << SHIFT;
      sel[b * 4] = pref;
      sel[b * 4 + 1] = krem - cum;  // ties at threshold to include
    }
  }
}

// ---------------------------------------------------------------------------
// Sum values strictly above the exact threshold. Grid (8, BB) x 256.
// ---------------------------------------------------------------------------
__global__ __launch_bounds__(256) void k_sumtop(
    const float* __restrict__ lossm, const unsigned* __restrict__ sel,
    double* __restrict__ accC) {
  const int b = blockIdx.y;
  const int tid = threadIdx.x;
  const unsigned pref = sel[b * 4];
  const float4* v4 = reinterpret_cast<const float4*>(lossm + (size_t)b * PP) +
                     (size_t)blockIdx.x * 4096;
  double s = 0.0;
#pragma unroll 4
  for (int k = 0; k < 16; ++k) {
    const float4 x = v4[tid + k * 256];
    if (__float_as_uint(x.x) > pref) s += (double)x.x;
    if (__float_as_uint(x.y) > pref) s += (double)x.y;
    if (__float_as_uint(x.z) > pref) s += (double)x.z;
    if (__float_as_uint(x.w) > pref) s += (double)x.w;
  }
#pragma unroll
  for (int off = 1; off < 64; off <<= 1) s += __shfl_xor(s, off, 64);
  __shared__ double rs[4];
  const int wave = tid >> 6, lane = tid & 63;
  if (lane == 0) rs[wave] = s;
  __syncthreads();
  if (tid == 0) atomicAdd(&accC[b], rs[0] + rs[1] + rs[2] + rs[3]);
}

// ---------------------------------------------------------------------------
// K4: finalize -> d_out[3] = {loss_l/N, loss_c/N, loss_coords/N}
// Adds the krem*thr tie contribution per batch.
// ---------------------------------------------------------------------------
__global__ void k_final(const double* __restrict__ accL,
                        const double* __restrict__ accC,
                        const double* __restrict__ accLM,
                        const int* __restrict__ numpos,
                        const unsigned* __restrict__ sel,
                        float* __restrict__ out) {
  if (threadIdx.x == 0 && blockIdx.x == 0) {
    long long tot = 0;
    double sl = 0, sc = 0, sm = 0;
    for (int b = 0; b < BB; ++b) {
      tot += numpos[b];
      sl += accL[b];
      sc += accC[b];
      const unsigned krem = sel[b * 4 + 1];
      if (krem > 0)
        sc += (double)krem * (double)__uint_as_float(sel[b * 4]);
      sm += accLM[b];
    }
    float N = (float)tot;
    if (N < 1.f) N = 1.f;
    out[0] = (float)(sl / (double)N);
    out[1] = (float)(sc / (double)N);
    out[2] = (float)(sm / (double)N);
  }
}

extern "C" void kernel_launch(void* const* d_in, const int* in_sizes, int n_in,
                              void* d_out, int out_size, void* d_ws,
                              size_t ws_size, hipStream_t stream) {
  const float* loc = (const float*)d_in[0];
  const float* conf = (const float*)d_in[1];
  const float* loc5 = (const float*)d_in[2];
  const float* priors = (const float*)d_in[3];
  const float* tgt = (const float*)d_in[4];
  char* ws = (char*)d_ws;
  double* accL = (double*)(ws + OFF_ACCL);
  double* accC = (double*)(ws + OFF_ACCC);
  double* accLM = (double*)(ws + OFF_ACCLM);
  int* numpos = (int*)(ws + OFF_NP);
  unsigned long long* slots = (unsigned long long*)(ws + OFF_SLOT);
  unsigned char* bti = (unsigned char*)(ws + OFF_BTI);
  float* lossm = (float*)(ws + OFF_LM);
  unsigned* hist = (unsigned*)(ws + OFF_HIST);  // aliases bti (dead by then)
  unsigned* sel = (unsigned*)(ws + OFF_SEL);

  // zero accumulators + argmax slots (first 9216 bytes)
  hipMemsetAsync(d_ws, 0, OFF_SLOT + (size_t)BB * AA * 8, stream);

  dim3 grid(PP / 2048, BB);
  k_match<<<grid, 256, 0, stream>>>(priors, tgt, slots, bti);
  k_loss<<<grid, 256, 0, stream>>>(loc, conf, loc5, priors, tgt, slots, bti,
                                   lossm, accL, accC, accLM, numpos);
  // bti is dead from here; reuse its storage for the radix histograms
  hipMemsetAsync(ws + OFF_HIST, 0, (size_t)BB * 2048 * 4, stream);
  dim3 hgrid(8, BB);
  k_hist<21, 11><<<hgrid, 256, 0, stream>>>(lossm, sel, hist);
  k_select<21, 11, true><<<BB, 256, 0, stream>>>(hist, sel, numpos);
  k_hist<10, 11><<<hgrid, 256, 0, stream>>>(lossm, sel, hist);
  k_select<10, 11, false><<<BB, 256, 0, stream>>>(hist, sel, numpos);
  k_hist<0, 10><<<hgrid, 256, 0, stream>>>(lossm, sel, hist);
  k_select<0, 10, false><<<BB, 256, 0, stream>>>(hist, sel, numpos);
  k_sumtop<<<hgrid, 256, 0, stream>>>(lossm, sel, accC);
  k_final<<<1, 64, 0, stream>>>(accL, accC, accLM, numpos, sel,
                                (float*)d_out);
}